// Round 5
// baseline (48.987 us; speedup 1.0000x reference)
//
#include <hip/hip_runtime.h>

// CollectAtomTriples: N=50000 atoms, K=32 neighbors each (uniform).
// P = K*(K-1)/2 = 496 triples per atom.
// Outputs (int32, concatenated in d_out):
//   idx_i[t] = a                       (t = a*P + p)
//   idx_j[t] = a*K + jj[p]
//   idx_k[t] = a*K + kk[p]
// where (jj,kk) = triu_indices(K, k=1) row-major (torch.combinations order).
//
// Pure write-streaming kernel: 297.6 MB of int32 stores, no input reads.
// LESSON (r2): keep each 16B store instruction lane-contiguous; wider
//   per-thread grouping stripes lanes, halving store density. No NT stores.
// LESSON (r4): stream separation per-block is neutral — not DRAM-row-bound.
// THIS ROUND: persistent grid-stride at 2048 blocks (8/CU) to remove ~34k
//   block dispatches + ramp/tail raggedness (Guideline 11).

#define NATOMS 50000
#define KNB    32
#define PPAIRS 496                 // KNB*(KNB-1)/2
#define NP     (NATOMS * PPAIRS)   // 24,800,000 elements per output array
#define GROUPS (NP / 4)            // 6,200,000 4-triple groups
#define NBLK   2048
#define NTHR   256

struct PairTab { unsigned short v[PPAIRS]; };

static constexpr PairTab make_tab() {
    PairTab t{};
    int p = 0;
    for (int j = 0; j < KNB; ++j)
        for (int k = j + 1; k < KNB; ++k)
            t.v[p++] = (unsigned short)((j << 8) | k);
    return t;
}

__constant__ PairTab c_tab = make_tab();

typedef int            int4v    __attribute__((ext_vector_type(4)));
typedef unsigned short ushort4v __attribute__((ext_vector_type(4)));

__device__ __forceinline__ void emit_group(int* __restrict__ out, int t0) {
    const unsigned int atom = (unsigned int)t0 / PPAIRS;  // magic-mul div
    const int p0   = t0 - (int)atom * PPAIRS;             // multiple of 4
    const int base = (int)atom * KNB;

    const ushort4v e = *(const ushort4v*)&c_tab.v[p0];    // 8B-aligned

    int4v vi, vj, vk;
    #pragma unroll
    for (int q = 0; q < 4; ++q) {
        const unsigned short ev = e[q];
        vi[q] = (int)atom;
        vj[q] = base + (int)(ev >> 8);
        vk[q] = base + (int)(ev & 0xFF);
    }

    // Lane-contiguous 16B stores; NP*4 and 2*NP*4 are multiples of 16.
    *(int4v*)&out[t0]          = vi;
    *(int4v*)&out[NP + t0]     = vj;
    *(int4v*)&out[2 * NP + t0] = vk;
}

__global__ __launch_bounds__(NTHR) void collect_triples_kernel(int* __restrict__ out) {
    const int stride = NBLK * NTHR;            // 524,288 threads
    for (int g = blockIdx.x * NTHR + threadIdx.x; g < GROUPS; g += stride)
        emit_group(out, g << 2);
}

extern "C" void kernel_launch(void* const* d_in, const int* in_sizes, int n_in,
                              void* d_out, int out_size, void* d_ws, size_t ws_size,
                              hipStream_t stream) {
    (void)d_in; (void)in_sizes; (void)n_in; (void)d_ws; (void)ws_size; (void)out_size;
    collect_triples_kernel<<<NBLK, NTHR, 0, stream>>>((int*)d_out);
}

// Round 6
// 46.612 us; speedup vs baseline: 1.0509x; 1.0509x over previous
//
#include <hip/hip_runtime.h>

// CollectAtomTriples: N=50000 atoms, K=32 neighbors each (uniform).
// P = K*(K-1)/2 = 496 triples per atom.
// Outputs (int32, concatenated in d_out):
//   idx_i[t] = a                       (t = a*P + p)
//   idx_j[t] = a*K + jj[p]
//   idx_k[t] = a*K + kk[p]
// where (jj,kk) = triu_indices(K, k=1) row-major (torch.combinations order).
//
// Pure write-streaming kernel: 297.6 MB of int32 stores, no input reads.
// ROOFLINE MODEL (r1-r5): steady-state write BW ≈ 7.15 TB/s (fillBuffer on
// this chip) + ~5 µs fixed launch/ramp => floor ≈ 46.6 µs. This kernel
// measures 46.6 µs. Refuted alternatives: 8-triple/thread + NT stores
// (r2: 2.6x WORSE — lane striping halves per-instruction store density),
// per-array block split (r4: neutral), persistent 2048-block grid-stride
// (r5: -5%). Keep: flat launch, 2 lane-contiguous 4-triple groups/thread.

#define NATOMS 50000
#define KNB    32
#define PPAIRS 496                 // KNB*(KNB-1)/2
#define NP     (NATOMS * PPAIRS)   // 24,800,000 elements per output array
#define GROUPS (NP / 4)            // 6,200,000 4-triple groups
#define HALFG  (GROUPS / 2)        // 3,100,000 threads, 2 groups each

struct PairTab { unsigned short v[PPAIRS]; };

static constexpr PairTab make_tab() {
    PairTab t{};
    int p = 0;
    for (int j = 0; j < KNB; ++j)
        for (int k = j + 1; k < KNB; ++k)
            t.v[p++] = (unsigned short)((j << 8) | k);
    return t;
}

__constant__ PairTab c_tab = make_tab();

typedef int            int4v    __attribute__((ext_vector_type(4)));
typedef unsigned short ushort4v __attribute__((ext_vector_type(4)));

__device__ __forceinline__ void emit_group(int* __restrict__ out, int t0) {
    const unsigned int atom = (unsigned int)t0 / PPAIRS;  // magic-mul div
    const int p0   = t0 - (int)atom * PPAIRS;             // multiple of 4
    const int base = (int)atom * KNB;

    const ushort4v e = *(const ushort4v*)&c_tab.v[p0];    // 8B-aligned

    int4v vi, vj, vk;
    #pragma unroll
    for (int q = 0; q < 4; ++q) {
        const unsigned short ev = e[q];
        vi[q] = (int)atom;
        vj[q] = base + (int)(ev >> 8);
        vk[q] = base + (int)(ev & 0xFF);
    }

    // Lane-contiguous 16B stores; NP*4 and 2*NP*4 are multiples of 16.
    *(int4v*)&out[t0]          = vi;
    *(int4v*)&out[NP + t0]     = vj;
    *(int4v*)&out[2 * NP + t0] = vk;
}

__global__ __launch_bounds__(256) void collect_triples_kernel(int* __restrict__ out) {
    const int g = blockIdx.x * 256 + threadIdx.x;
    if (g >= HALFG) return;
    emit_group(out, g << 2);                    // first half
    emit_group(out, (g << 2) + (NP / 2));       // second half (NP/2 % 4 == 0)
}

extern "C" void kernel_launch(void* const* d_in, const int* in_sizes, int n_in,
                              void* d_out, int out_size, void* d_ws, size_t ws_size,
                              hipStream_t stream) {
    (void)d_in; (void)in_sizes; (void)n_in; (void)d_ws; (void)ws_size; (void)out_size;
    const int blocks = (HALFG + 255) / 256;     // 12,110
    collect_triples_kernel<<<blocks, 256, 0, stream>>>((int*)d_out);
}